// Round 1
// baseline (386.347 us; speedup 1.0000x reference)
//
#include <hip/hip_runtime.h>
#include <hip/hip_bf16.h>

typedef __hip_bfloat16 bf16;
typedef __attribute__((ext_vector_type(8))) short bf16x8;   // 8 bf16 = 4 VGPRs
typedef __attribute__((ext_vector_type(4))) float f32x4;

static constexpr int SEQ = 2048;   // sequence length
static constexpr int HDIM = 1024;  // H*D
static constexpr int NH = 16;      // heads
static constexpr int DH = 64;      // per-head dim
static constexpr int MROWS = 4096; // B*S

__device__ __forceinline__ f32x4 mfma16(bf16x8 a, bf16x8 b, f32x4 c) {
  return __builtin_amdgcn_mfma_f32_16x16x32_bf16(a, b, c, 0, 0, 0);
}

// async global->LDS, 16B per lane; LDS dest must be wave-uniform base (lane*16 implicit)
__device__ __forceinline__ void gload_lds16(const bf16* g, bf16* l) {
  __builtin_amdgcn_global_load_lds(
      (const __attribute__((address_space(1))) void*)g,
      (__attribute__((address_space(3))) void*)l, 16, 0, 0);
}

// ---------------- fp32 -> bf16 convert (vectorized) ----------------
__global__ __launch_bounds__(256) void cvt_bf16(const float* __restrict__ in,
                                                bf16* __restrict__ out, int n4) {
  int i = blockIdx.x * blockDim.x + threadIdx.x;
  if (i >= n4) return;
  float4 v = reinterpret_cast<const float4*>(in)[i];
  bf16 t[4] = {__float2bfloat16(v.x), __float2bfloat16(v.y),
               __float2bfloat16(v.z), __float2bfloat16(v.w)};
  reinterpret_cast<ushort4*>(out)[i] = *reinterpret_cast<ushort4*>(t);
}

// ---------------- GEMM core: C[128x128] += A[128xK] * W[128xK]^T ----------------
// A row-major [M x K], W row-major [N x K] (torch Linear weight == B^T layout).
// 4 waves in 2x2; each wave 64x64 = 4x4 frags of 16x16x32 MFMA. BK=32.
__device__ __forceinline__ void gemm_core(const bf16* __restrict__ A,
                                          const bf16* __restrict__ W,
                                          int m0, int n0, int K,
                                          f32x4 (&acc)[4][4],
                                          bf16* As, bf16* Bs) {
  const int tid = threadIdx.x;
  const int w = tid >> 6, lane = tid & 63;
  const int wr = w >> 1, wc = w & 1;
  const int lr = lane & 15, lk = (lane >> 4) * 8;
  const int srow = lane >> 2, scol = (lane & 3) * 8;  // staging: row-within-chunk, col

  for (int kt = 0; kt < K; kt += 32) {
#pragma unroll
    for (int j = 0; j < 2; ++j) {
      int cidx = w * 2 + j;           // chunk 0..7, 16 rows each
      int r = cidx * 16 + srow;
      gload_lds16(A + (size_t)(m0 + r) * K + kt + scol, As + cidx * 512);
      gload_lds16(W + (size_t)(n0 + r) * K + kt + scol, Bs + cidx * 512);
    }
    __syncthreads();  // drains vmcnt before use
    bf16x8 af[4], bw[4];
#pragma unroll
    for (int i = 0; i < 4; ++i)
      af[i] = *reinterpret_cast<const bf16x8*>(As + (wr * 64 + i * 16 + lr) * 32 + lk);
#pragma unroll
    for (int i = 0; i < 4; ++i)
      bw[i] = *reinterpret_cast<const bf16x8*>(Bs + (wc * 64 + i * 16 + lr) * 32 + lk);
#pragma unroll
    for (int r = 0; r < 4; ++r)
#pragma unroll
      for (int c = 0; c < 4; ++c)
        acc[r][c] = mfma16(af[r], bw[c], acc[r][c]);
    __syncthreads();
  }
}

// ---------------- fused QKV projection ----------------
// z=0: Q -> [B,H,S,D] bf16, pre-scaled by 1/sqrt(D)
// z=1: K -> [B,H,S,D] bf16
// z=2: V -> [B,H,D,S] bf16 (transposed, for contiguous PV B-fragments)
__global__ __launch_bounds__(256)
void qkv_gemm(const bf16* __restrict__ xb,
              const bf16* __restrict__ wq, const bf16* __restrict__ wk,
              const bf16* __restrict__ wv,
              const float* __restrict__ bq, const float* __restrict__ bk,
              const float* __restrict__ bv,
              bf16* __restrict__ qd, bf16* __restrict__ kd, bf16* __restrict__ vT) {
  __shared__ bf16 As[128 * 32], Bs[128 * 32];
  const int z = blockIdx.z;
  const bf16* W = (z == 0) ? wq : (z == 1) ? wk : wv;
  const float* bias = (z == 0) ? bq : (z == 1) ? bk : bv;
  const float scale = (z == 0) ? 0.125f : 1.0f;  // 1/sqrt(64), exact in bf16
  const int m0 = blockIdx.y * 128, n0 = blockIdx.x * 128;
  f32x4 acc[4][4] = {};
  gemm_core(xb, W, m0, n0, HDIM, acc, As, Bs);

  const int tid = threadIdx.x, w = tid >> 6, lane = tid & 63;
  const int wr = w >> 1, wc = w & 1;
  const int lr = lane & 15, rg = (lane >> 4) * 4;
#pragma unroll
  for (int r = 0; r < 4; ++r)
#pragma unroll
    for (int c = 0; c < 4; ++c) {
      int n = n0 + wc * 64 + c * 16 + lr;  // C/D: col = lane&15
      int h = n >> 6, d = n & 63;
      float bz = bias[n];
#pragma unroll
      for (int q = 0; q < 4; ++q) {        // C/D: row = (lane>>4)*4 + reg
        int m = m0 + wr * 64 + r * 16 + rg + q;
        int b = m >> 11, s = m & 2047;
        bf16 val = __float2bfloat16((acc[r][c][q] + bz) * scale);
        if (z == 2)
          vT[(((size_t)(b * NH + h) * DH + d) << 11) + s] = val;
        else {
          bf16* dst = (z == 0) ? qd : kd;
          dst[(((size_t)(b * NH + h) * SEQ + s) << 6) + d] = val;
        }
      }
    }
}

// ---------------- flash attention ----------------
// grid (S/64, B*H); 4 waves/block, each wave owns 16 q-rows, iterates 32-row K tiles.
__global__ __launch_bounds__(256)
void attn_kernel(const bf16* __restrict__ Q, const bf16* __restrict__ K,
                 const bf16* __restrict__ vT, bf16* __restrict__ AO) {
  __shared__ bf16 Plds[4][16 * 32];  // per-wave P tile (no cross-wave sharing)
  const int lane = threadIdx.x & 63;
  const int w = threadIdx.x >> 6;
  const int bh = blockIdx.y;
  const int b = bh >> 4, h = bh & 15;
  const int q0 = blockIdx.x * 64 + w * 16;
  const int lr = lane & 15, lk = (lane >> 4) * 8;
  const int prow = (lane >> 4) * 4;

  const bf16* Qh = Q + (size_t)bh * SEQ * DH;
  const bf16* Kh = K + (size_t)bh * SEQ * DH;
  const bf16* Vh = vT + (size_t)bh * DH * SEQ;

  // Q A-fragments (row = lane&15, k = (lane>>4)*8+i), D=64 -> 2 k-steps
  bf16x8 aq0 = *reinterpret_cast<const bf16x8*>(Qh + (size_t)(q0 + lr) * DH + lk);
  bf16x8 aq1 = *reinterpret_cast<const bf16x8*>(Qh + (size_t)(q0 + lr) * DH + 32 + lk);

  f32x4 o[4] = {};                       // 16 rows x 64 d-cols accumulator
  float mrow[4] = {-1e30f, -1e30f, -1e30f, -1e30f};
  float lrow[4] = {0.f, 0.f, 0.f, 0.f};
  bf16* pl = &Plds[w][0];

  for (int kt = 0; kt < SEQ; kt += 32) {
    // K B-fragments: col = k-row (lane&15 within 16), k = d
    const bf16* kb = Kh + (size_t)(kt + lr) * DH + lk;
    bf16x8 b00 = *reinterpret_cast<const bf16x8*>(kb);
    bf16x8 b01 = *reinterpret_cast<const bf16x8*>(kb + 32);
    bf16x8 b10 = *reinterpret_cast<const bf16x8*>(kb + 16 * DH);
    bf16x8 b11 = *reinterpret_cast<const bf16x8*>(kb + 16 * DH + 32);
    f32x4 s0 = {}, s1 = {};
    s0 = mfma16(aq0, b00, s0); s0 = mfma16(aq1, b01, s0);  // cols kt..kt+15
    s1 = mfma16(aq0, b10, s1); s1 = mfma16(aq1, b11, s1);  // cols kt+16..kt+31

    // online softmax: row r lives in 16 lanes (cols) of this lane's group
    float alpha[4], p0[4], p1[4];
#pragma unroll
    for (int r = 0; r < 4; ++r) {
      float pm = fmaxf(s0[r], s1[r]);
      pm = fmaxf(pm, __shfl_xor(pm, 1));
      pm = fmaxf(pm, __shfl_xor(pm, 2));
      pm = fmaxf(pm, __shfl_xor(pm, 4));
      pm = fmaxf(pm, __shfl_xor(pm, 8));
      float mn = fmaxf(mrow[r], pm);
      alpha[r] = exp2f((mrow[r] - mn) * 1.44269504f);
      mrow[r] = mn;
      p0[r] = exp2f((s0[r] - mn) * 1.44269504f);
      p1[r] = exp2f((s1[r] - mn) * 1.44269504f);
      float ps = p0[r] + p1[r];
      ps += __shfl_xor(ps, 1);
      ps += __shfl_xor(ps, 2);
      ps += __shfl_xor(ps, 4);
      ps += __shfl_xor(ps, 8);
      lrow[r] = lrow[r] * alpha[r] + ps;
    }

    // P: C-layout -> A-layout via per-wave LDS (DS ops in-order within a wave)
#pragma unroll
    for (int r = 0; r < 4; ++r) {
      pl[(prow + r) * 32 + lr] = __float2bfloat16(p0[r]);
      pl[(prow + r) * 32 + 16 + lr] = __float2bfloat16(p1[r]);
    }
    __builtin_amdgcn_wave_barrier();  // keep compiler from reordering write/read
    bf16x8 ap = *reinterpret_cast<const bf16x8*>(pl + lr * 32 + lk);

    // PV: B from transposed V (row = d, contiguous in k-row)
    const bf16* vb = Vh + (size_t)lr * SEQ + kt + lk;
#pragma unroll
    for (int c = 0; c < 4; ++c) {
#pragma unroll
      for (int r = 0; r < 4; ++r) o[c][r] *= alpha[r];
      bf16x8 bv = *reinterpret_cast<const bf16x8*>(vb + (size_t)(c * 16) * SEQ);
      o[c] = mfma16(ap, bv, o[c]);
    }
  }

  // epilogue: AO is [B,S,H*D] bf16 (heads re-concatenated)
#pragma unroll
  for (int r = 0; r < 4; ++r) {
    float inv = 1.0f / lrow[r];
    int srow = q0 + prow + r;
#pragma unroll
    for (int c = 0; c < 4; ++c)
      AO[(size_t)(b * SEQ + srow) * HDIM + h * DH + c * 16 + lr] =
          __float2bfloat16(o[c][r] * inv);
  }
}

// ---------------- final projection: fp32 out ----------------
__global__ __launch_bounds__(256)
void fc_gemm(const bf16* __restrict__ A, const bf16* __restrict__ W,
             const float* __restrict__ bias, float* __restrict__ out) {
  __shared__ bf16 As[128 * 32], Bs[128 * 32];
  const int m0 = blockIdx.y * 128, n0 = blockIdx.x * 128;
  f32x4 acc[4][4] = {};
  gemm_core(A, W, m0, n0, HDIM, acc, As, Bs);

  const int tid = threadIdx.x, w = tid >> 6, lane = tid & 63;
  const int wr = w >> 1, wc = w & 1;
  const int lr = lane & 15, rg = (lane >> 4) * 4;
#pragma unroll
  for (int r = 0; r < 4; ++r)
#pragma unroll
    for (int c = 0; c < 4; ++c) {
      int n = n0 + wc * 64 + c * 16 + lr;
      float bz = bias[n];
#pragma unroll
      for (int q = 0; q < 4; ++q) {
        int m = m0 + wr * 64 + r * 16 + rg + q;
        out[(size_t)m * HDIM + n] = acc[r][c][q] + bz;
      }
    }
}

extern "C" void kernel_launch(void* const* d_in, const int* in_sizes, int n_in,
                              void* d_out, int out_size, void* d_ws, size_t ws_size,
                              hipStream_t stream) {
  (void)in_sizes; (void)n_in; (void)out_size; (void)ws_size;
  const float* x  = (const float*)d_in[0];
  const float* wq = (const float*)d_in[1];
  const float* bq = (const float*)d_in[2];
  const float* wk = (const float*)d_in[3];
  const float* bk = (const float*)d_in[4];
  const float* wv = (const float*)d_in[5];
  const float* bv = (const float*)d_in[6];
  const float* wf = (const float*)d_in[7];
  const float* bf_ = (const float*)d_in[8];
  float* out = (float*)d_out;

  char* ws = (char*)d_ws;
  bf16* xb  = (bf16*)(ws);                  // 8 MB  [4096 x 1024]
  bf16* wqb = (bf16*)(ws + (8u << 20));     // 2 MB each
  bf16* wkb = (bf16*)(ws + (10u << 20));
  bf16* wvb = (bf16*)(ws + (12u << 20));
  bf16* wfb = (bf16*)(ws + (14u << 20));
  bf16* qd  = (bf16*)(ws + (16u << 20));    // 8 MB [B,H,S,D]
  bf16* kd  = (bf16*)(ws + (24u << 20));    // 8 MB [B,H,S,D]
  bf16* vT  = (bf16*)(ws + (32u << 20));    // 8 MB [B,H,D,S]
  bf16* ao  = (bf16*)(ws + (40u << 20));    // 8 MB [B,S,H*D]

  cvt_bf16<<<4096, 256, 0, stream>>>(x, xb, 1048576);
  cvt_bf16<<<1024, 256, 0, stream>>>(wq, wqb, 262144);
  cvt_bf16<<<1024, 256, 0, stream>>>(wk, wkb, 262144);
  cvt_bf16<<<1024, 256, 0, stream>>>(wv, wvb, 262144);
  cvt_bf16<<<1024, 256, 0, stream>>>(wf, wfb, 262144);

  qkv_gemm<<<dim3(8, 32, 3), 256, 0, stream>>>(xb, wqb, wkb, wvb, bq, bk, bv,
                                               qd, kd, vT);
  attn_kernel<<<dim3(32, 32), 256, 0, stream>>>(qd, kd, vT, ao);
  fc_gemm<<<dim3(8, 32), 256, 0, stream>>>(ao, wfb, bf_, out);
}

// Round 2
// 273.794 us; speedup vs baseline: 1.4111x; 1.4111x over previous
//
#include <hip/hip_runtime.h>
#include <hip/hip_bf16.h>

typedef __hip_bfloat16 bf16;
typedef __attribute__((ext_vector_type(8))) short bf16x8;   // 8 bf16 = 4 VGPRs
typedef __attribute__((ext_vector_type(4))) float f32x4;
typedef __attribute__((ext_vector_type(16))) float f32x16;

static constexpr int SEQ = 2048;   // sequence length
static constexpr int HDIM = 1024;  // H*D
static constexpr int NH = 16;      // heads
static constexpr int DH = 64;      // per-head dim

__device__ __forceinline__ f32x4 mfma16(bf16x8 a, bf16x8 b, f32x4 c) {
  return __builtin_amdgcn_mfma_f32_16x16x32_bf16(a, b, c, 0, 0, 0);
}
__device__ __forceinline__ f32x16 mfma32(bf16x8 a, bf16x8 b, f32x16 c) {
  return __builtin_amdgcn_mfma_f32_32x32x16_bf16(a, b, c, 0, 0, 0);
}

// async global->LDS, 16B per lane; LDS dest must be wave-uniform base (lane*16 implicit)
__device__ __forceinline__ void gload_lds16(const bf16* g, bf16* l) {
  __builtin_amdgcn_global_load_lds(
      (const __attribute__((address_space(1))) void*)g,
      (__attribute__((address_space(3))) void*)l, 16, 0, 0);
}

__device__ __forceinline__ unsigned packbf(float a, float b) {
  unsigned short ua = __builtin_bit_cast(unsigned short, __float2bfloat16(a));
  unsigned short ub = __builtin_bit_cast(unsigned short, __float2bfloat16(b));
  return (unsigned)ua | ((unsigned)ub << 16);
}

// ---------------- fp32 -> bf16 convert (vectorized) ----------------
__global__ __launch_bounds__(256) void cvt_bf16(const float* __restrict__ in,
                                                bf16* __restrict__ out, int n4) {
  int i = blockIdx.x * blockDim.x + threadIdx.x;
  if (i >= n4) return;
  float4 v = reinterpret_cast<const float4*>(in)[i];
  bf16 t[4] = {__float2bfloat16(v.x), __float2bfloat16(v.y),
               __float2bfloat16(v.z), __float2bfloat16(v.w)};
  reinterpret_cast<ushort4*>(out)[i] = *reinterpret_cast<ushort4*>(t);
}

// ---------------- GEMM core: C[128x128] += A[128xK] * W[128xK]^T ----------------
__device__ __forceinline__ void gemm_core(const bf16* __restrict__ A,
                                          const bf16* __restrict__ W,
                                          int m0, int n0, int K,
                                          f32x4 (&acc)[4][4],
                                          bf16* As, bf16* Bs) {
  const int tid = threadIdx.x;
  const int w = tid >> 6, lane = tid & 63;
  const int wr = w >> 1, wc = w & 1;
  const int lr = lane & 15, lk = (lane >> 4) * 8;
  const int srow = lane >> 2, scol = (lane & 3) * 8;

  for (int kt = 0; kt < K; kt += 32) {
#pragma unroll
    for (int j = 0; j < 2; ++j) {
      int cidx = w * 2 + j;
      int r = cidx * 16 + srow;
      gload_lds16(A + (size_t)(m0 + r) * K + kt + scol, As + cidx * 512);
      gload_lds16(W + (size_t)(n0 + r) * K + kt + scol, Bs + cidx * 512);
    }
    __syncthreads();
    bf16x8 af[4], bw[4];
#pragma unroll
    for (int i = 0; i < 4; ++i)
      af[i] = *reinterpret_cast<const bf16x8*>(As + (wr * 64 + i * 16 + lr) * 32 + lk);
#pragma unroll
    for (int i = 0; i < 4; ++i)
      bw[i] = *reinterpret_cast<const bf16x8*>(Bs + (wc * 64 + i * 16 + lr) * 32 + lk);
#pragma unroll
    for (int r = 0; r < 4; ++r)
#pragma unroll
      for (int c = 0; c < 4; ++c)
        acc[r][c] = mfma16(af[r], bw[c], acc[r][c]);
    __syncthreads();
  }
}

// ---------------- fused QKV projection ----------------
__global__ __launch_bounds__(256)
void qkv_gemm(const bf16* __restrict__ xb,
              const bf16* __restrict__ wq, const bf16* __restrict__ wk,
              const bf16* __restrict__ wv,
              const float* __restrict__ bq, const float* __restrict__ bk,
              const float* __restrict__ bv,
              bf16* __restrict__ qd, bf16* __restrict__ kd, bf16* __restrict__ vT) {
  __shared__ bf16 As[128 * 32], Bs[128 * 32];
  const int z = blockIdx.z;
  const bf16* W = (z == 0) ? wq : (z == 1) ? wk : wv;
  const float* bias = (z == 0) ? bq : (z == 1) ? bk : bv;
  const float scale = (z == 0) ? 0.125f : 1.0f;  // 1/sqrt(64)
  const int m0 = blockIdx.y * 128, n0 = blockIdx.x * 128;
  f32x4 acc[4][4] = {};
  gemm_core(xb, W, m0, n0, HDIM, acc, As, Bs);

  const int tid = threadIdx.x, w = tid >> 6, lane = tid & 63;
  const int wr = w >> 1, wc = w & 1;
  const int lr = lane & 15, rg = (lane >> 4) * 4;
#pragma unroll
  for (int r = 0; r < 4; ++r)
#pragma unroll
    for (int c = 0; c < 4; ++c) {
      int n = n0 + wc * 64 + c * 16 + lr;
      int h = n >> 6, d = n & 63;
      float bz = bias[n];
#pragma unroll
      for (int q = 0; q < 4; ++q) {
        int m = m0 + wr * 64 + r * 16 + rg + q;
        int b = m >> 11, s = m & 2047;
        bf16 val = __float2bfloat16((acc[r][c][q] + bz) * scale);
        if (z == 2)
          vT[(((size_t)(b * NH + h) * DH + d) << 11) + s] = val;
        else {
          bf16* dst = (z == 0) ? qd : kd;
          dst[(((size_t)(b * NH + h) * SEQ + s) << 6) + d] = val;
        }
      }
    }
}

// ---------------- flash attention, swapped-QK^T in-register softmax ----------------
// grid (S/128, B*H); 4 waves/block, each wave owns 32 q-rows, 32-row K tiles.
// S[k][q] = mfma32(K_frag, Q_frag): col=lane&31=q, rows = 16 k per lane.
__global__ __launch_bounds__(256)
void attn_kernel(const bf16* __restrict__ Q, const bf16* __restrict__ K,
                 const bf16* __restrict__ vT, bf16* __restrict__ AO) {
  __shared__ float als[4][32];   // per-wave alpha / l broadcast
  const int lane = threadIdx.x & 63;
  const int wv = threadIdx.x >> 6;
  const int l31 = lane & 31;
  const int hi = lane >> 5;
  const int bh = blockIdx.y;
  const int b = bh >> 4, h = bh & 15;
  const int q0 = blockIdx.x * 128 + wv * 32;

  const bf16* Qh = Q + (size_t)bh * SEQ * DH;
  const bf16* Kh = K + (size_t)bh * SEQ * DH;
  const bf16* Vh = vT + (size_t)bh * DH * SEQ;

  // Q B-frags hoisted: col=q=l31, k-elems d = step*16 + hi*8 + i
  bf16x8 qf[4];
#pragma unroll
  for (int s = 0; s < 4; ++s)
    qf[s] = *reinterpret_cast<const bf16x8*>(
        Qh + (size_t)(q0 + l31) * DH + s * 16 + hi * 8);

  f32x16 o0 = {}, o1 = {};           // O[q-set][d], d = {0..31, 32..63}
  float m = -1e30f, l = 0.f;         // softmax state for q = l31 (dup across hi)

  for (int kt = 0; kt < SEQ; kt += 32) {
    // QK^T swapped: A = K (row=k, contiguous d), B = Q (col=q)
    f32x16 sacc = {};
#pragma unroll
    for (int s = 0; s < 4; ++s) {
      bf16x8 kf = *reinterpret_cast<const bf16x8*>(
          Kh + (size_t)(kt + l31) * DH + s * 16 + hi * 8);
      sacc = mfma32(kf, qf[s], sacc);
    }
    // V B-frags: col=d (within tile), k-elems contiguous from vT[d][k]
    bf16x8 vf[2][2];
#pragma unroll
    for (int kh = 0; kh < 2; ++kh)
#pragma unroll
      for (int t = 0; t < 2; ++t)
        vf[kh][t] = *reinterpret_cast<const bf16x8*>(
            Vh + (size_t)(t * 32 + l31) * SEQ + kt + kh * 16 + hi * 8);

    // online softmax: lane holds 16 k-values for its q; rest via 1 shfl_xor(32)
    float pmax = sacc[0];
#pragma unroll
    for (int i = 1; i < 16; ++i) pmax = fmaxf(pmax, sacc[i]);
    pmax = fmaxf(pmax, __shfl_xor(pmax, 32));

    if (__any(pmax > m + 8.0f)) {    // defer-max: rescale only when max grows
      float mn = fmaxf(m, pmax);
      float al = exp2f((m - mn) * 1.442695041f);  // first tile: exp2(-inf)=0
      m = mn; l *= al;
      if (lane < 32) als[wv][l31] = al;
      __builtin_amdgcn_wave_barrier();
#pragma unroll
      for (int r = 0; r < 16; ++r) {
        float a = als[wv][(r & 3) + 8 * (r >> 2) + 4 * hi];
        o0[r] *= a; o1[r] *= a;
      }
      __builtin_amdgcn_wave_barrier();
    }

    const float mc = m * 1.442695041f;
    float p[16];
    float ps = 0.f;
#pragma unroll
    for (int i = 0; i < 16; ++i) {
      p[i] = exp2f(sacc[i] * 1.442695041f - mc);
      ps += p[i];
    }
    ps += __shfl_xor(ps, 32);
    l += ps;

    // pack P to bf16 pairs; one cross-half exchange builds PV A-frags.
    // lane reg r holds P[k=(r&3)+8*(r>>2)+4*hi][q=l31]; group g=r>>2 covers
    // k in {8g+4hi .. 8g+4hi+3}.
    unsigned w[4][2], sw[4][2];
#pragma unroll
    for (int g = 0; g < 4; ++g) {
      w[g][0] = packbf(p[4 * g + 0], p[4 * g + 1]);
      w[g][1] = packbf(p[4 * g + 2], p[4 * g + 3]);
      sw[g][0] = __shfl_xor(w[g][0], 32);
      sw[g][1] = __shfl_xor(w[g][1], 32);
    }
#pragma unroll
    for (int kh = 0; kh < 2; ++kh) {
      // A-frag (row=q=l31, k = kh*16 + hi*8 + i):
      //   hi=0: [w[2kh][0], w[2kh][1], sw[2kh][0], sw[2kh][1]]
      //   hi=1: [sw[2kh+1][0], sw[2kh+1][1], w[2kh+1][0], w[2kh+1][1]]
      union { unsigned u[4]; bf16x8 v; } fa;
      fa.u[0] = hi ? sw[2 * kh + 1][0] : w[2 * kh][0];
      fa.u[1] = hi ? sw[2 * kh + 1][1] : w[2 * kh][1];
      fa.u[2] = hi ? w[2 * kh + 1][0] : sw[2 * kh][0];
      fa.u[3] = hi ? w[2 * kh + 1][1] : sw[2 * kh][1];
      o0 = mfma32(fa.v, vf[kh][0], o0);
      o1 = mfma32(fa.v, vf[kh][1], o1);
    }
  }

  // epilogue: transpose l through LDS (O rows are reg-mapped q, l is lane-mapped)
  if (lane < 32) als[wv][l31] = l;
  __builtin_amdgcn_wave_barrier();
#pragma unroll
  for (int r = 0; r < 16; ++r) {
    int q = (r & 3) + 8 * (r >> 2) + 4 * hi;
    float inv = 1.0f / als[wv][q];
    size_t row = (size_t)(b * SEQ + q0 + q) * HDIM + h * DH;
    AO[row + l31] = __float2bfloat16(o0[r] * inv);
    AO[row + 32 + l31] = __float2bfloat16(o1[r] * inv);
  }
}

// ---------------- final projection: fp32 out ----------------
__global__ __launch_bounds__(256)
void fc_gemm(const bf16* __restrict__ A, const bf16* __restrict__ W,
             const float* __restrict__ bias, float* __restrict__ out) {
  __shared__ bf16 As[128 * 32], Bs[128 * 32];
  const int m0 = blockIdx.y * 128, n0 = blockIdx.x * 128;
  f32x4 acc[4][4] = {};
  gemm_core(A, W, m0, n0, HDIM, acc, As, Bs);

  const int tid = threadIdx.x, w = tid >> 6, lane = tid & 63;
  const int wr = w >> 1, wc = w & 1;
  const int lr = lane & 15, rg = (lane >> 4) * 4;
#pragma unroll
  for (int r = 0; r < 4; ++r)
#pragma unroll
    for (int c = 0; c < 4; ++c) {
      int n = n0 + wc * 64 + c * 16 + lr;
      float bz = bias[n];
#pragma unroll
      for (int q = 0; q < 4; ++q) {
        int m = m0 + wr * 64 + r * 16 + rg + q;
        out[(size_t)m * HDIM + n] = acc[r][c][q] + bz;
      }
    }
}

extern "C" void kernel_launch(void* const* d_in, const int* in_sizes, int n_in,
                              void* d_out, int out_size, void* d_ws, size_t ws_size,
                              hipStream_t stream) {
  (void)in_sizes; (void)n_in; (void)out_size; (void)ws_size;
  const float* x  = (const float*)d_in[0];
  const float* wq = (const float*)d_in[1];
  const float* bq = (const float*)d_in[2];
  const float* wk = (const float*)d_in[3];
  const float* bk = (const float*)d_in[4];
  const float* wv = (const float*)d_in[5];
  const float* bv = (const float*)d_in[6];
  const float* wf = (const float*)d_in[7];
  const float* bf_ = (const float*)d_in[8];
  float* out = (float*)d_out;

  char* ws = (char*)d_ws;
  bf16* xb  = (bf16*)(ws);                  // 8 MB  [4096 x 1024]
  bf16* wqb = (bf16*)(ws + (8u << 20));     // 2 MB each
  bf16* wkb = (bf16*)(ws + (10u << 20));
  bf16* wvb = (bf16*)(ws + (12u << 20));
  bf16* wfb = (bf16*)(ws + (14u << 20));
  bf16* qd  = (bf16*)(ws + (16u << 20));    // 8 MB [B,H,S,D]
  bf16* kd  = (bf16*)(ws + (24u << 20));    // 8 MB [B,H,S,D]
  bf16* vT  = (bf16*)(ws + (32u << 20));    // 8 MB [B,H,D,S]
  bf16* ao  = (bf16*)(ws + (40u << 20));    // 8 MB [B,S,H*D]

  cvt_bf16<<<4096, 256, 0, stream>>>(x, xb, 1048576);
  cvt_bf16<<<1024, 256, 0, stream>>>(wq, wqb, 262144);
  cvt_bf16<<<1024, 256, 0, stream>>>(wk, wkb, 262144);
  cvt_bf16<<<1024, 256, 0, stream>>>(wv, wvb, 262144);
  cvt_bf16<<<1024, 256, 0, stream>>>(wf, wfb, 262144);

  qkv_gemm<<<dim3(8, 32, 3), 256, 0, stream>>>(xb, wqb, wkb, wvb, bq, bk, bv,
                                               qd, kd, vT);
  attn_kernel<<<dim3(16, 32), 256, 0, stream>>>(qd, kd, vT, ao);
  fc_gemm<<<dim3(8, 32), 256, 0, stream>>>(ao, wfb, bf_, out);
}